// Round 3
// baseline (164.941 us; speedup 1.0000x reference)
//
#include <hip/hip_runtime.h>

// FullyConnectedTP (e3nn FCTP, MUL=16), R3: register-only, DPP row reduction.
//
// Per edge n:
//   out0[j]    = PW0*( C[j]*v0 + D[j]*inv3 ),             j=0..15
//   out1[w][k] = PW1*inv3*( A[w]*v1[k] + B[k][w]*v0 ),    w=0..15,k=0..2
// with C[j]=sum_u w1[u][j]u0[u], D[j]=sum_u w4[u][j]d4[u],
//      A[w]=sum_u w2[u][w]u0[u], B[k][w]=sum_u w3[u][w]u1[u][k],
//      d4[u]=dot(u1[u,:],v1).
//
// One wave per edge. lane -> (u = lane&15, c = lane>>4). Each lane loads the
// float4 [u][4c..4c+3] of each of the 4 weight matrices (4 coalesced
// global_load_dwordx4 covering the whole 4KB block), forms 20 partials, and
// the sum over u is a reduction across the 16 lanes of a DPP row
// (v_mov_b32_dpp row_ror:8/4/2/1 + v_add). No LDS, no barriers.

template <int CTRL>
__device__ __forceinline__ float row_rot_add(float x) {
    int t = __builtin_amdgcn_update_dpp(0, __float_as_int(x), CTRL, 0xF, 0xF, false);
    return x + __int_as_float(t);
}
__device__ __forceinline__ float rowsum16(float x) {
    x = row_rot_add<0x128>(x);   // row_ror:8
    x = row_rot_add<0x124>(x);   // row_ror:4
    x = row_rot_add<0x122>(x);   // row_ror:2
    x = row_rot_add<0x121>(x);   // row_ror:1
    return x;                    // every lane in the 16-lane row holds the sum
}
__device__ __forceinline__ float sel4(float a, float b, float c, float d, int i) {
    float r = (i == 1) ? b : a;
    r = (i == 2) ? c : r;
    r = (i == 3) ? d : r;
    return r;
}

__global__ __launch_bounds__(256) void fctp_kernel(
    const float* __restrict__ U,
    const float* __restrict__ V,
    const float* __restrict__ W,
    float* __restrict__ out,
    int N)
{
    constexpr float INV_SQRT3 = 0.57735026918962576451f; // 1/sqrt(3)
    constexpr float PW0 = 0.17677669529663688110f;       // sqrt(1/32)
    constexpr float PW1 = 0.30618621784789726f;          // sqrt(3/32)

    const int lane = threadIdx.x & 63;
    const int wv   = threadIdx.x >> 6;
    int n = blockIdx.x * 4 + wv;
    if (n >= N) n = N - 1;   // N%4==0 in practice; benign deterministic redo

    const int u = lane & 15;   // u index == position within DPP row
    const int c = lane >> 4;   // float4-column group == DPP row index

    // ---- weight block: 4 coalesced dwordx4 loads cover all 4KB ----
    const float4* wq = (const float4*)(W + (size_t)n * 1024);
    const int fi = u * 4 + c;            // float4 index inside one 1KB matrix
    const float4 L1 = wq[  0 + fi];      // w1[u][4c..4c+3]
    const float4 L2 = wq[ 64 + fi];      // w2
    const float4 L3 = wq[128 + fi];      // w3
    const float4 L4 = wq[192 + fi];      // w4

    // ---- per-lane coefficients ----
    const float4 vv = ((const float4*)V)[n];
    const float v0 = vv.x;
    const float* up = U + (size_t)n * 64;
    const float u0  = up[u];
    const float u10 = up[16 + 3 * u + 0];
    const float u11 = up[16 + 3 * u + 1];
    const float u12 = up[16 + 3 * u + 2];
    const float d4  = u10 * vv.y + u11 * vv.z + u12 * vv.w;

    const float a1 = u0 * v0;          // multiplies w1
    const float a4 = d4 * INV_SQRT3;   // multiplies w4

    // ---- partials (20 floats) ----
    float p0x = L1.x * a1 + L4.x * a4;
    float p0y = L1.y * a1 + L4.y * a4;
    float p0z = L1.z * a1 + L4.z * a4;
    float p0w = L1.w * a1 + L4.w * a4;

    float pa0 = L2.x * u0, pa1 = L2.y * u0, pa2 = L2.z * u0, pa3 = L2.w * u0;

    float b00 = L3.x * u10, b01 = L3.y * u10, b02 = L3.z * u10, b03 = L3.w * u10;
    float b10 = L3.x * u11, b11 = L3.y * u11, b12 = L3.z * u11, b13 = L3.w * u11;
    float b20 = L3.x * u12, b21 = L3.y * u12, b22 = L3.z * u12, b23 = L3.w * u12;

    // ---- reduce over u (across the 16 lanes of this DPP row) ----
    p0x = rowsum16(p0x); p0y = rowsum16(p0y); p0z = rowsum16(p0z); p0w = rowsum16(p0w);
    pa0 = rowsum16(pa0); pa1 = rowsum16(pa1); pa2 = rowsum16(pa2); pa3 = rowsum16(pa3);
    b00 = rowsum16(b00); b01 = rowsum16(b01); b02 = rowsum16(b02); b03 = rowsum16(b03);
    b10 = rowsum16(b10); b11 = rowsum16(b11); b12 = rowsum16(b12); b13 = rowsum16(b13);
    b20 = rowsum16(b20); b21 = rowsum16(b21); b22 = rowsum16(b22); b23 = rowsum16(b23);

    // ---- epilogue: each lane writes exactly one of the 64 outputs ----
    float val;
    int oidx;
    if (u < 4) {
        // out0[4c + u]
        float r = sel4(p0x, p0y, p0z, p0w, u);
        val  = PW0 * r;
        oidx = 4 * c + u;
    } else {
        // out1[w=4c+i][k], flat 16 + 12c + j, j = 3i+k = u-4
        const int j = u - 4;
        const int i = (j * 11) >> 5;   // j/3 for j in 0..11
        const int k = j - 3 * i;
        const float ra  = sel4(pa0, pa1, pa2, pa3, i);
        const float vk  = (k == 0) ? vv.y : (k == 1) ? vv.z : vv.w;
        const float rb0 = sel4(b00, b01, b02, b03, i);
        const float rb1 = sel4(b10, b11, b12, b13, i);
        const float rb2 = sel4(b20, b21, b22, b23, i);
        const float rb  = (k == 0) ? rb0 : (k == 1) ? rb1 : rb2;
        val  = PW1 * INV_SQRT3 * (ra * vk + v0 * rb);
        oidx = 16 + 12 * c + j;
    }
    out[(size_t)n * 64 + oidx] = val;
}

extern "C" void kernel_launch(void* const* d_in, const int* in_sizes, int n_in,
                              void* d_out, int out_size, void* d_ws, size_t ws_size,
                              hipStream_t stream)
{
    const float* U = (const float*)d_in[0];
    const float* V = (const float*)d_in[1];
    const float* W = (const float*)d_in[2];
    float* out = (float*)d_out;

    const int N = in_sizes[1] / 4;   // v is (N,4)
    const int blocks = (N + 3) / 4;  // 4 edges (one wave each) per 256-thread block
    fctp_kernel<<<blocks, 256, 0, stream>>>(U, V, W, out, N);
}